// Round 1
// baseline (623.498 us; speedup 1.0000x reference)
//
#include <hip/hip_runtime.h>
#include <math.h>

// XMIX mixing network, fused fp32 baseline.
// B = 32768 samples, TB = 16 samples per block, 2048 blocks x 256 threads.
// LDS: S (y-tile, also holds states first) 32KB + Bf1/Bf2 16KB each + small = 74KB
// -> 2 blocks/CU.

#define TB 16
#define NB 32768

__global__ __launch_bounds__(256, 2) void xmix_fused(
    const float* __restrict__ agent_qs,
    const float* __restrict__ states,
    const float* __restrict__ W_tok, const float* __restrict__ b_tok,
    const float* __restrict__ W_yfc, const float* __restrict__ b_yfc,
    const float* __restrict__ W1a,  const float* __restrict__ b1a,
    const float* __restrict__ W1b,  const float* __restrict__ b1b,
    const float* __restrict__ Wfa,  const float* __restrict__ bfa,
    const float* __restrict__ Wfb,  const float* __restrict__ bfb,
    const float* __restrict__ Wb1,  const float* __restrict__ bb1,
    const float* __restrict__ Wv1,  const float* __restrict__ bv1,
    const float* __restrict__ Wv2,  const float* __restrict__ bv2,
    float* __restrict__ out)
{
    __shared__ float S[TB][512];    // states, then y
    __shared__ float Bf1[TB][256];  // e, then h1, then w1
    __shared__ float Bf2[TB][256];  // hf
    __shared__ float b1s[TB][32];
    __shared__ float v1s[TB][32];
    __shared__ float wfs[TB][32];
    __shared__ float hids[TB][32];
    __shared__ float tprod[TB][32];

    const int tid = threadIdx.x;
    const int blk = blockIdx.x;
    const int base = blk * TB;  // first sample index of this block

    // ---- P0: load states tile (16 x 512 floats) ----
    {
        const float4* src = (const float4*)(states + (size_t)base * 512);
        float4* dst = (float4*)&S[0][0];
        #pragma unroll
        for (int i = 0; i < 8; i++) dst[tid + 256 * i] = src[tid + 256 * i];
    }
    __syncthreads();

    // ---- P1: e = relu(s @ W_tok + b_tok)  -> Bf1[s][a*32+j] ----
    {
        const int j = tid & 31, a = tid >> 5;  // 8 agents x 32 emb = 256 threads
        float acc[TB];
        #pragma unroll
        for (int s = 0; s < TB; s++) acc[s] = 0.f;
        for (int f = 0; f < 64; f += 4) {
            const float w0 = W_tok[(f + 0) * 32 + j];
            const float w1 = W_tok[(f + 1) * 32 + j];
            const float w2 = W_tok[(f + 2) * 32 + j];
            const float w3 = W_tok[(f + 3) * 32 + j];
            #pragma unroll
            for (int s = 0; s < TB; s++) {
                const float4 sv = *(const float4*)&S[s][a * 64 + f];
                acc[s] = fmaf(sv.x, w0, acc[s]);
                acc[s] = fmaf(sv.y, w1, acc[s]);
                acc[s] = fmaf(sv.z, w2, acc[s]);
                acc[s] = fmaf(sv.w, w3, acc[s]);
            }
        }
        const float bt = b_tok[j];
        #pragma unroll
        for (int s = 0; s < TB; s++) Bf1[s][a * 32 + j] = fmaxf(acc[s] + bt, 0.f);
    }
    __syncthreads();

    // ---- P2: y = relu(e @ W_yfc + b_yfc) -> overwrite S (states fully consumed) ----
    {
        const int f = tid & 63, ag = tid >> 6;  // ag in 0..3, 2 agents each
        const float bv = b_yfc[f];
        #pragma unroll
        for (int aa = 0; aa < 2; aa++) {
            const int a = ag * 2 + aa;
            float acc[TB];
            #pragma unroll
            for (int s = 0; s < TB; s++) acc[s] = 0.f;
            for (int j = 0; j < 32; j += 4) {
                const float w0 = W_yfc[(j + 0) * 64 + f];
                const float w1 = W_yfc[(j + 1) * 64 + f];
                const float w2 = W_yfc[(j + 2) * 64 + f];
                const float w3 = W_yfc[(j + 3) * 64 + f];
                #pragma unroll
                for (int s = 0; s < TB; s++) {
                    const float4 ev = *(const float4*)&Bf1[s][a * 32 + j];
                    acc[s] = fmaf(ev.x, w0, acc[s]);
                    acc[s] = fmaf(ev.y, w1, acc[s]);
                    acc[s] = fmaf(ev.z, w2, acc[s]);
                    acc[s] = fmaf(ev.w, w3, acc[s]);
                }
            }
            #pragma unroll
            for (int s = 0; s < TB; s++) S[s][a * 64 + f] = fmaxf(acc[s] + bv, 0.f);
        }
    }
    __syncthreads();

    // ---- P3: h1 = relu(y@W1a + b1a) -> Bf1 ; hf = relu(y@Wfa + bfa) -> Bf2 ----
    {
        const int c = tid;  // 256 columns
        float acc1[TB], accf[TB];
        #pragma unroll
        for (int s = 0; s < TB; s++) { acc1[s] = 0.f; accf[s] = 0.f; }
        for (int k = 0; k < 512; k += 4) {
            const float wa0 = W1a[(k + 0) * 256 + c];
            const float wa1 = W1a[(k + 1) * 256 + c];
            const float wa2 = W1a[(k + 2) * 256 + c];
            const float wa3 = W1a[(k + 3) * 256 + c];
            const float wb0 = Wfa[(k + 0) * 256 + c];
            const float wb1 = Wfa[(k + 1) * 256 + c];
            const float wb2 = Wfa[(k + 2) * 256 + c];
            const float wb3 = Wfa[(k + 3) * 256 + c];
            #pragma unroll
            for (int s = 0; s < TB; s++) {
                const float4 yv = *(const float4*)&S[s][k];
                acc1[s] = fmaf(yv.x, wa0, acc1[s]);
                acc1[s] = fmaf(yv.y, wa1, acc1[s]);
                acc1[s] = fmaf(yv.z, wa2, acc1[s]);
                acc1[s] = fmaf(yv.w, wa3, acc1[s]);
                accf[s] = fmaf(yv.x, wb0, accf[s]);
                accf[s] = fmaf(yv.y, wb1, accf[s]);
                accf[s] = fmaf(yv.z, wb2, accf[s]);
                accf[s] = fmaf(yv.w, wb3, accf[s]);
            }
        }
        const float ba = b1a[c], bf = bfa[c];
        #pragma unroll
        for (int s = 0; s < TB; s++) {
            Bf1[s][c] = fmaxf(acc1[s] + ba, 0.f);   // e consumed in P2, safe
            Bf2[s][c] = fmaxf(accf[s] + bf, 0.f);
        }
    }
    // ---- P3b: b1 = y@Wb1 + bb1 ; v1 = relu(y@Wv1 + bv1) ----
    {
        const int c = tid & 63, sg = tid >> 6;  // 4 sample-groups of 4
        float acc[4];
        #pragma unroll
        for (int i = 0; i < 4; i++) acc[i] = 0.f;
        const float* Wp = (c < 32) ? (Wb1 + c) : (Wv1 + (c - 32));
        for (int k = 0; k < 512; k += 4) {
            const float w0 = Wp[(k + 0) * 32];
            const float w1 = Wp[(k + 1) * 32];
            const float w2 = Wp[(k + 2) * 32];
            const float w3 = Wp[(k + 3) * 32];
            #pragma unroll
            for (int i = 0; i < 4; i++) {
                const float4 yv = *(const float4*)&S[sg * 4 + i][k];
                acc[i] = fmaf(yv.x, w0, acc[i]);
                acc[i] = fmaf(yv.y, w1, acc[i]);
                acc[i] = fmaf(yv.z, w2, acc[i]);
                acc[i] = fmaf(yv.w, w3, acc[i]);
            }
        }
        if (c < 32) {
            const float bb = bb1[c];
            #pragma unroll
            for (int i = 0; i < 4; i++) b1s[sg * 4 + i][c] = acc[i] + bb;
        } else {
            const float bv = bv1[c - 32];
            #pragma unroll
            for (int i = 0; i < 4; i++) v1s[sg * 4 + i][c - 32] = fmaxf(acc[i] + bv, 0.f);
        }
    }
    __syncthreads();

    // ---- P4: w1 = |h1 @ W1b + b1b| ; wf = |hf @ Wfb + bfb| ----
    {
        const int c = tid;
        float acc[TB];
        #pragma unroll
        for (int s = 0; s < TB; s++) acc[s] = 0.f;
        for (int u = 0; u < 256; u += 4) {
            const float w0 = W1b[(u + 0) * 256 + c];
            const float w1 = W1b[(u + 1) * 256 + c];
            const float w2 = W1b[(u + 2) * 256 + c];
            const float w3 = W1b[(u + 3) * 256 + c];
            #pragma unroll
            for (int s = 0; s < TB; s++) {
                const float4 hv = *(const float4*)&Bf1[s][u];
                acc[s] = fmaf(hv.x, w0, acc[s]);
                acc[s] = fmaf(hv.y, w1, acc[s]);
                acc[s] = fmaf(hv.z, w2, acc[s]);
                acc[s] = fmaf(hv.w, w3, acc[s]);
            }
        }
        const float bb = b1b[c];
        float wreg[TB];
        #pragma unroll
        for (int s = 0; s < TB; s++) wreg[s] = fabsf(acc[s] + bb);

        const int cf = tid & 31, sg2 = tid >> 5;  // 8 groups x 2 samples
        float accw[2] = {0.f, 0.f};
        for (int u = 0; u < 256; u += 4) {
            const float q0 = Wfb[(u + 0) * 32 + cf];
            const float q1 = Wfb[(u + 1) * 32 + cf];
            const float q2 = Wfb[(u + 2) * 32 + cf];
            const float q3 = Wfb[(u + 3) * 32 + cf];
            #pragma unroll
            for (int i = 0; i < 2; i++) {
                const float4 hv = *(const float4*)&Bf2[sg2 * 2 + i][u];
                accw[i] = fmaf(hv.x, q0, accw[i]);
                accw[i] = fmaf(hv.y, q1, accw[i]);
                accw[i] = fmaf(hv.z, q2, accw[i]);
                accw[i] = fmaf(hv.w, q3, accw[i]);
            }
        }
        const float bfv = bfb[cf];
        __syncthreads();  // all reads of Bf1/Bf2 complete before overwrite
        #pragma unroll
        for (int s = 0; s < TB; s++) Bf1[s][c] = wreg[s];  // w1 (flat 8x32)
        #pragma unroll
        for (int i = 0; i < 2; i++) wfs[sg2 * 2 + i][cf] = fabsf(accw[i] + bfv);
    }
    __syncthreads();

    // ---- P5: epilogue per sample ----
    {
        const int s = tid >> 4;   // 16 samples
        const int l = tid & 15;   // 16 threads per sample
        const int b = base + s;
        float q[8];
        #pragma unroll
        for (int a = 0; a < 8; a++) q[a] = agent_qs[b * 8 + a];
        #pragma unroll
        for (int ee = 0; ee < 2; ee++) {
            const int e = l + 16 * ee;
            float z = b1s[s][e];
            #pragma unroll
            for (int a = 0; a < 8; a++) z = fmaf(q[a], Bf1[s][a * 32 + e], z);
            const float h = (z > 0.f) ? z : (expf(z) - 1.f);   // elu
            const float d = (h < 0.f) ? expf(h) : 1.f;         // delu of ELU OUTPUT (ref!)
            hids[s][e] = h;
            tprod[s][e] = d * wfs[s][e];
        }
    }
    __syncthreads();
    {
        const int s = tid >> 4;
        const int l = tid & 15;
        const int b = base + s;
        if (l == 0) {
            float v = bv2[0];
            #pragma unroll
            for (int e = 0; e < 32; e++) v = fmaf(v1s[s][e], Wv2[e], v);
            float qt = v;
            #pragma unroll
            for (int e = 0; e < 32; e++) qt = fmaf(hids[s][e], wfs[s][e], qt);
            out[b] = qt;
        } else if (l < 9) {
            const int a = l - 1;
            float g = 0.f;
            #pragma unroll
            for (int e = 0; e < 32; e++) g = fmaf(Bf1[s][a * 32 + e], tprod[s][e], g);
            out[NB + b * 8 + a] = g;
        }
    }
}

extern "C" void kernel_launch(void* const* d_in, const int* in_sizes, int n_in,
                              void* d_out, int out_size, void* d_ws, size_t ws_size,
                              hipStream_t stream) {
    const float* agent_qs = (const float*)d_in[0];
    // d_in[1] = hist (unused by reference)
    const float* states   = (const float*)d_in[2];
    // d_in[3] = obs (unused by reference)
    const float* W_tok = (const float*)d_in[4];
    const float* b_tok = (const float*)d_in[5];
    const float* W_yfc = (const float*)d_in[6];
    const float* b_yfc = (const float*)d_in[7];
    const float* W1a   = (const float*)d_in[8];
    const float* b1a   = (const float*)d_in[9];
    const float* W1b   = (const float*)d_in[10];
    const float* b1b   = (const float*)d_in[11];
    const float* Wfa   = (const float*)d_in[12];
    const float* bfa   = (const float*)d_in[13];
    const float* Wfb   = (const float*)d_in[14];
    const float* bfb   = (const float*)d_in[15];
    const float* Wb1   = (const float*)d_in[16];
    const float* bb1   = (const float*)d_in[17];
    const float* Wv1   = (const float*)d_in[18];
    const float* bv1   = (const float*)d_in[19];
    const float* Wv2   = (const float*)d_in[20];
    const float* bv2   = (const float*)d_in[21];
    float* out = (float*)d_out;

    xmix_fused<<<NB / TB, 256, 0, stream>>>(
        agent_qs, states, W_tok, b_tok, W_yfc, b_yfc,
        W1a, b1a, W1b, b1b, Wfa, bfa, Wfb, bfb,
        Wb1, bb1, Wv1, bv1, Wv2, bv2, out);
}